// Round 5
// baseline (612.340 us; speedup 1.0000x reference)
//
#include <hip/hip_runtime.h>
#include <math.h>

#define N_NODES 50000
#define N_EDGES 800000
#define DIN 128
#define DH 256
#define DOUT 64
#define NLAYERS 4

typedef unsigned short u16;
typedef __attribute__((ext_vector_type(8))) _Float16 half8;
typedef __attribute__((ext_vector_type(4))) float f32x4;

__device__ inline u16 f2h(float f) {
  _Float16 h = (_Float16)f;
  return *(u16*)&h;
}
__device__ inline float h2f(u16 u) {
  _Float16 h = *(_Float16*)&u;
  return (float)h;
}

// ---------------- preprocessing ----------------

__global__ void k_count(const int* __restrict__ dst, int* __restrict__ cnt, int e) {
  int i = blockIdx.x * blockDim.x + threadIdx.x;
  if (i < e) atomicAdd(&cnt[dst[i]], 1);
}

// scan1 + dinv fused
__global__ void k_scan1(const int* __restrict__ cnt, int* __restrict__ rowptr,
                        int* __restrict__ bsum, float* __restrict__ dinv, int n) {
  __shared__ int sm[256];
  int i = blockIdx.x * 256 + threadIdx.x;
  int v = (i < n) ? cnt[i] : 0;
  if (i < n) dinv[i] = rsqrtf((float)v + 1.0f);  // +1 = self-loop
  sm[threadIdx.x] = v;
  __syncthreads();
  for (int off = 1; off < 256; off <<= 1) {
    int t = (threadIdx.x >= off) ? sm[threadIdx.x - off] : 0;
    __syncthreads();
    sm[threadIdx.x] += t;
    __syncthreads();
  }
  if (i < n) rowptr[i + 1] = sm[threadIdx.x];
  if (threadIdx.x == 255) bsum[blockIdx.x] = sm[255];
}

__global__ void k_scan2(int* bsum, int nb) {
  __shared__ int sm[256];
  int v = (threadIdx.x < nb) ? bsum[threadIdx.x] : 0;
  sm[threadIdx.x] = v;
  __syncthreads();
  for (int off = 1; off < 256; off <<= 1) {
    int t = (threadIdx.x >= off) ? sm[threadIdx.x - off] : 0;
    __syncthreads();
    sm[threadIdx.x] += t;
    __syncthreads();
  }
  if (threadIdx.x < nb) bsum[threadIdx.x] = sm[threadIdx.x] - v;
}

// scan3 + cursor init fused
__global__ void k_scan3(int* __restrict__ rowptr, const int* __restrict__ bsum,
                        int* __restrict__ cursor, int n) {
  int i = blockIdx.x * 256 + threadIdx.x;
  if (i < n) {
    int v = rowptr[i + 1] + bsum[blockIdx.x];
    rowptr[i + 1] = v;
    if (i + 1 < n) cursor[i + 1] = v;
  }
  if (blockIdx.x == 0 && threadIdx.x == 0) {
    rowptr[0] = 0;
    cursor[0] = 0;
  }
}

__global__ void k_fill(const int* __restrict__ src, const int* __restrict__ dst,
                       const float* __restrict__ dinv,
                       int* __restrict__ cursor, int2* __restrict__ csr, int e) {
  int i = blockIdx.x * blockDim.x + threadIdx.x;
  if (i < e) {
    int d = dst[i], s = src[i];
    int pos = atomicAdd(&cursor[d], 1);
    csr[pos] = make_int2(s, __float_as_int(dinv[s] * dinv[d]));
  }
}

// ---------------- conversions (x + all weights, one kernel) ----------------
// Bt layouts: plain Bt[n*K + k] = f16(W[k*N + n]); out split: [n][kp], kp<256 hi,
// 256..512 lo, 512..768 hi.
#define X_Q (N_NODES * DIN / 4)        // 1,600,000 float4 groups
#define W_EMB_SZ (DIN * DH)            // 32768
#define W_CONV_SZ (DH * DH)            // 65536
#define W_OUT_SZ (3 * DH * DOUT)       // 49152
#define W_TOT (W_EMB_SZ + 4 * W_CONV_SZ + W_OUT_SZ)

__global__ void k_convert(const float* __restrict__ x, u16* __restrict__ x_f16,
                          const float* __restrict__ W_emb, const float* __restrict__ W_conv,
                          const float* __restrict__ W_out, u16* __restrict__ Bt_emb,
                          u16* __restrict__ Bt_conv, u16* __restrict__ Bt_out) {
  int i = blockIdx.x * 256 + threadIdx.x;
  if (i < X_Q) {
    float4 v = ((const float4*)x)[i];
    ushort4 o;
    o.x = f2h(v.x); o.y = f2h(v.y); o.z = f2h(v.z); o.w = f2h(v.w);
    ((ushort4*)x_f16)[i] = o;
    return;
  }
  int t = i - X_Q;
  if (t < W_EMB_SZ) {
    int n = t >> 7, k = t & (DIN - 1);
    Bt_emb[t] = f2h(W_emb[k * DH + n]);
  } else if (t < W_EMB_SZ + 4 * W_CONV_SZ) {
    int j = t - W_EMB_SZ;
    int l = j >> 16, jj = j & (W_CONV_SZ - 1);
    int n = jj >> 8, k = jj & (DH - 1);
    Bt_conv[j] = f2h(W_conv[l * W_CONV_SZ + k * DH + n]);
  } else if (t < W_TOT) {
    int j = t - W_EMB_SZ - 4 * W_CONV_SZ;
    int n = j / (3 * DH), kp = j % (3 * DH);
    int k = (kp < DH) ? kp : ((kp < 2 * DH) ? kp - DH : kp - 2 * DH);
    float wv = W_out[k * DOUT + n];
    u16 hiv = f2h(wv);
    u16 v = hiv;
    if (kp >= DH && kp < 2 * DH) v = f2h(wv - h2f(hiv));
    Bt_out[j] = v;
  }
}

// ---------------- f16 MFMA GEMM, LDS-free ----------------
// Each wave computes an independent 64x64 tile of C = A·B (+bias), loading A/B
// fragments straight from global (B is L2-resident weight; A segments are the
// same 16x64B lines LDS staging would fetch). No barriers, no LDS.
// A: (Ahi, Alo) f16 [M][K]. NSPLIT=1: C=Ahi·Bhi. NSPLIT=3: hi·hi + hi·lo + lo·hi
// with Bt segments [0,K) hi, [K,2K) lo, [2K,3K) hi. Bt = B^T [N][NSPLIT*K] f16.
// EPI 0: Cf fp32 (+bias); EPI 1: Cb f16 (+bias).
template <int NSPLIT, int EPI>
__global__ __launch_bounds__(256) void k_gemm_direct(
    const u16* __restrict__ Ahi, const u16* __restrict__ Alo,
    const u16* __restrict__ Bt, const float* __restrict__ bias,
    float* __restrict__ Cf, u16* __restrict__ Cb, int M, int K, int N) {
  const int lane = threadIdx.x & 63;
  const int w = threadIdx.x >> 6;
  const int q = lane >> 4, r = lane & 15;
  const int ntiles = N >> 6;
  const int mtiles = (M + 63) >> 6;
  int waveId = blockIdx.x * 4 + w;
  if (waveId >= mtiles * ntiles) return;
  // n-minor: the 4 waves of a block share A rows (L1 reuse) when ntiles>=4
  int ntile = waveId % ntiles;
  int mtile = waveId / ntiles;
  const int m0 = mtile * 64, n0 = ntile * 64;
  const int Kp = NSPLIT * K;

  int rowA[4];
#pragma unroll
  for (int t = 0; t < 4; t++) {
    int rr = m0 + t * 16 + r;
    rowA[t] = (rr < M) ? rr : (M - 1);
  }

  f32x4 acc[4][4];
#pragma unroll
  for (int t = 0; t < 4; t++)
#pragma unroll
    for (int u = 0; u < 4; u++) acc[t][u] = (f32x4){0.f, 0.f, 0.f, 0.f};

  for (int s = 0; s < NSPLIT; s++) {
    const u16* Aseg = (s == 2) ? Alo : Ahi;
    const u16* Bseg = Bt + s * K;  // column offset within [N][Kp]
    for (int kk = 0; kk < K; kk += 32) {
      half8 af[4], bfr[4];
#pragma unroll
      for (int t = 0; t < 4; t++)
        af[t] = *(const half8*)(Aseg + (size_t)rowA[t] * K + kk + q * 8);
#pragma unroll
      for (int u = 0; u < 4; u++)
        bfr[u] = *(const half8*)(Bseg + (size_t)(n0 + u * 16 + r) * Kp + kk + q * 8);
#pragma unroll
      for (int t = 0; t < 4; t++)
#pragma unroll
        for (int u = 0; u < 4; u++)
          acc[t][u] = __builtin_amdgcn_mfma_f32_16x16x32_f16(af[t], bfr[u], acc[t][u], 0, 0, 0);
    }
  }

  float bv[4];
#pragma unroll
  for (int u = 0; u < 4; u++) bv[u] = bias ? bias[n0 + u * 16 + r] : 0.f;

#pragma unroll
  for (int t = 0; t < 4; t++) {
#pragma unroll
    for (int rg = 0; rg < 4; rg++) {
      int row = m0 + t * 16 + q * 4 + rg;
      if (row < M) {
#pragma unroll
        for (int u = 0; u < 4; u++) {
          int col = n0 + u * 16 + r;
          float v = acc[t][u][rg] + bv[u];
          if (EPI == 0)
            Cf[(size_t)row * N + col] = v;
          else
            Cb[(size_t)row * N + col] = f2h(v);
        }
      }
    }
  }
}

// ---------------- aggregation (f16 in, unroll-8 gathers) ----------------
// h[i] = tanh(b + dinv[i]^2*tmp[i] + sum_e w_e*tmp[src_e]); writes f16 hi (+lo).
__global__ void k_aggregate(const u16* __restrict__ tmph,
                            const int* __restrict__ rowptr, const int2* __restrict__ csr,
                            const float* __restrict__ dinv, const float* __restrict__ bias,
                            u16* __restrict__ hi, u16* __restrict__ lo, int n) {
  int i = (int)((blockIdx.x * (size_t)blockDim.x + threadIdx.x) >> 6);
  int lane = threadIdx.x & 63;
  if (i >= n) return;
  float w0 = dinv[i];
  w0 *= w0;
  const ushort4* T = (const ushort4*)tmph;
  float4 bv = ((const float4*)bias)[lane];
  ushort4 t0 = T[(size_t)i * 64 + lane];
  float ax = bv.x + w0 * h2f(t0.x);
  float ay = bv.y + w0 * h2f(t0.y);
  float az = bv.z + w0 * h2f(t0.z);
  float aw = bv.w + w0 * h2f(t0.w);
  int s = rowptr[i], e = rowptr[i + 1];
  int j = s;
  for (; j + 8 <= e; j += 8) {
    int2 c[8];
    ushort4 v[8];
#pragma unroll
    for (int u = 0; u < 8; u++) c[u] = csr[j + u];
#pragma unroll
    for (int u = 0; u < 8; u++) v[u] = T[(size_t)c[u].x * 64 + lane];
#pragma unroll
    for (int u = 0; u < 8; u++) {
      float f = __int_as_float(c[u].y);
      ax += f * h2f(v[u].x);
      ay += f * h2f(v[u].y);
      az += f * h2f(v[u].z);
      aw += f * h2f(v[u].w);
    }
  }
  for (; j + 4 <= e; j += 4) {
    int2 c[4];
    ushort4 v[4];
#pragma unroll
    for (int u = 0; u < 4; u++) c[u] = csr[j + u];
#pragma unroll
    for (int u = 0; u < 4; u++) v[u] = T[(size_t)c[u].x * 64 + lane];
#pragma unroll
    for (int u = 0; u < 4; u++) {
      float f = __int_as_float(c[u].y);
      ax += f * h2f(v[u].x);
      ay += f * h2f(v[u].y);
      az += f * h2f(v[u].z);
      aw += f * h2f(v[u].w);
    }
  }
  for (; j < e; j++) {
    int2 c = csr[j];
    ushort4 v = T[(size_t)c.x * 64 + lane];
    float f = __int_as_float(c.y);
    ax += f * h2f(v.x);
    ay += f * h2f(v.y);
    az += f * h2f(v.z);
    aw += f * h2f(v.w);
  }
  float ox = tanhf(ax), oy = tanhf(ay), oz = tanhf(az), ow = tanhf(aw);
  size_t base = (size_t)i * DH + lane * 4;
  ushort4 hv;
  hv.x = f2h(ox); hv.y = f2h(oy); hv.z = f2h(oz); hv.w = f2h(ow);
  *(ushort4*)(hi + base) = hv;
  if (lo) {
    ushort4 lv;
    lv.x = f2h(ox - h2f(hv.x));
    lv.y = f2h(oy - h2f(hv.y));
    lv.z = f2h(oz - h2f(hv.z));
    lv.w = f2h(ow - h2f(hv.w));
    *(ushort4*)(lo + base) = lv;
  }
}

// ---------------- launch ----------------

extern "C" void kernel_launch(void* const* d_in, const int* in_sizes, int n_in,
                              void* d_out, int out_size, void* d_ws, size_t ws_size,
                              hipStream_t stream) {
  const float* x = (const float*)d_in[0];
  const int* eidx = (const int*)d_in[1];
  const int* esrc = eidx;
  const int* edst = eidx + N_EDGES;
  const float* W_emb = (const float*)d_in[2];
  const float* b_emb = (const float*)d_in[3];
  const float* W_conv = (const float*)d_in[4];
  const float* b_conv = (const float*)d_in[5];
  const float* W_out = (const float*)d_in[6];
  const float* b_out = (const float*)d_in[7];
  float* out = (float*)d_out;

  char* ws = (char*)d_ws;
  size_t off = 0;
  auto alloc = [&](size_t bytes) -> void* {
    void* p = ws + off;
    off += (bytes + 255) & ~(size_t)255;
    return p;
  };
  u16* tmph = (u16*)alloc((size_t)N_NODES * DH * 2);
  u16* h_hi = (u16*)alloc((size_t)N_NODES * DH * 2);
  u16* h_lo = (u16*)alloc((size_t)N_NODES * DH * 2);
  u16* x_f16 = h_lo;  // alias: x_f16 dead after emb GEMM; h_lo first written at layer-3 agg
  float* dinv = (float*)alloc((size_t)N_NODES * 4);
  int* cnt = (int*)alloc((size_t)N_NODES * 4);
  int* rowptr = (int*)alloc((size_t)(N_NODES + 1) * 4);
  int* cursor = (int*)alloc((size_t)N_NODES * 4);
  int* bsum = (int*)alloc((size_t)((N_NODES + 255) / 256) * 4);
  int2* csr = (int2*)alloc((size_t)N_EDGES * 8);
  u16* Bt_emb = (u16*)alloc((size_t)W_EMB_SZ * 2);
  u16* Bt_conv = (u16*)alloc((size_t)4 * W_CONV_SZ * 2);
  u16* Bt_out = (u16*)alloc((size_t)W_OUT_SZ * 2);

  int nb = (N_NODES + 255) / 256;
  int eb = (N_EDGES + 255) / 256;

  hipMemsetAsync(cnt, 0, (size_t)N_NODES * 4, stream);
  k_count<<<eb, 256, 0, stream>>>(edst, cnt, N_EDGES);
  k_scan1<<<nb, 256, 0, stream>>>(cnt, rowptr, bsum, dinv, N_NODES);
  k_scan2<<<1, 256, 0, stream>>>(bsum, nb);
  k_scan3<<<nb, 256, 0, stream>>>(rowptr, bsum, cursor, N_NODES);
  k_fill<<<eb, 256, 0, stream>>>(esrc, edst, dinv, cursor, csr, N_EDGES);
  k_convert<<<(X_Q + W_TOT + 255) / 256, 256, 0, stream>>>(x, x_f16, W_emb, W_conv, W_out,
                                                           Bt_emb, Bt_conv, Bt_out);

  int mtiles = (N_NODES + 63) / 64;  // 782
  int aggblocks = (N_NODES * 64 + 255) / 256;

  // emb: h0 = x @ W_emb + b_emb  -> f16 h_hi   (782*4 waves = 782 blocks)
  k_gemm_direct<1, 1><<<(mtiles * (DH / 64) + 3) / 4, 256, 0, stream>>>(
      x_f16, nullptr, Bt_emb, b_emb, nullptr, h_hi, N_NODES, DIN, DH);
  // conv layers: plain f16; layer 3 agg also emits h_lo for the final split GEMM
  for (int l = 0; l < NLAYERS; l++) {
    k_gemm_direct<1, 1><<<(mtiles * (DH / 64) + 3) / 4, 256, 0, stream>>>(
        h_hi, nullptr, Bt_conv + (size_t)l * W_CONV_SZ, nullptr,
        nullptr, tmph, N_NODES, DH, DH);
    k_aggregate<<<aggblocks, 256, 0, stream>>>(tmph, rowptr, csr, dinv,
                                               b_conv + (size_t)l * DH,
                                               h_hi, (l == 3) ? h_lo : nullptr, N_NODES);
  }
  // out = h4 @ W_out + b_out (split-3, fp32 out)   (782 waves = 196 blocks)
  k_gemm_direct<3, 0><<<(mtiles * (DOUT / 64) + 3) / 4, 256, 0, stream>>>(
      h_hi, h_lo, Bt_out, b_out, out, nullptr, N_NODES, DH, DOUT);
}

// Round 6
// 566.684 us; speedup vs baseline: 1.0806x; 1.0806x over previous
//
#include <hip/hip_runtime.h>
#include <math.h>

#define N_NODES 50000
#define N_EDGES 800000
#define DIN 128
#define DH 256
#define DOUT 64
#define NLAYERS 4

typedef unsigned short u16;
typedef __attribute__((ext_vector_type(8))) _Float16 half8;
typedef __attribute__((ext_vector_type(4))) float f32x4;

__device__ inline u16 f2h(float f) {
  _Float16 h = (_Float16)f;
  return *(u16*)&h;
}
__device__ inline float h2f(u16 u) {
  _Float16 h = *(_Float16*)&u;
  return (float)h;
}

#define GLD16(gp, lp)                                                        \
  __builtin_amdgcn_global_load_lds(                                          \
      (const __attribute__((address_space(1))) void*)(const void*)(gp),      \
      (__attribute__((address_space(3))) void*)(void*)(lp), 16, 0, 0)

// ---------------- preprocessing ----------------

__global__ void k_count(const int* __restrict__ dst, int* __restrict__ cnt, int e) {
  int i = blockIdx.x * blockDim.x + threadIdx.x;
  if (i < e) atomicAdd(&cnt[dst[i]], 1);
}

// scan1 + dinv fused
__global__ void k_scan1(const int* __restrict__ cnt, int* __restrict__ rowptr,
                        int* __restrict__ bsum, float* __restrict__ dinv, int n) {
  __shared__ int sm[256];
  int i = blockIdx.x * 256 + threadIdx.x;
  int v = (i < n) ? cnt[i] : 0;
  if (i < n) dinv[i] = rsqrtf((float)v + 1.0f);  // +1 = self-loop
  sm[threadIdx.x] = v;
  __syncthreads();
  for (int off = 1; off < 256; off <<= 1) {
    int t = (threadIdx.x >= off) ? sm[threadIdx.x - off] : 0;
    __syncthreads();
    sm[threadIdx.x] += t;
    __syncthreads();
  }
  if (i < n) rowptr[i + 1] = sm[threadIdx.x];
  if (threadIdx.x == 255) bsum[blockIdx.x] = sm[255];
}

__global__ void k_scan2(int* bsum, int nb) {
  __shared__ int sm[256];
  int v = (threadIdx.x < nb) ? bsum[threadIdx.x] : 0;
  sm[threadIdx.x] = v;
  __syncthreads();
  for (int off = 1; off < 256; off <<= 1) {
    int t = (threadIdx.x >= off) ? sm[threadIdx.x - off] : 0;
    __syncthreads();
    sm[threadIdx.x] += t;
    __syncthreads();
  }
  if (threadIdx.x < nb) bsum[threadIdx.x] = sm[threadIdx.x] - v;
}

// scan3 + cursor init fused
__global__ void k_scan3(int* __restrict__ rowptr, const int* __restrict__ bsum,
                        int* __restrict__ cursor, int n) {
  int i = blockIdx.x * 256 + threadIdx.x;
  if (i < n) {
    int v = rowptr[i + 1] + bsum[blockIdx.x];
    rowptr[i + 1] = v;
    if (i + 1 < n) cursor[i + 1] = v;
  }
  if (blockIdx.x == 0 && threadIdx.x == 0) {
    rowptr[0] = 0;
    cursor[0] = 0;
  }
}

__global__ void k_fill(const int* __restrict__ src, const int* __restrict__ dst,
                       const float* __restrict__ dinv,
                       int* __restrict__ cursor, int2* __restrict__ csr, int e) {
  int i = blockIdx.x * blockDim.x + threadIdx.x;
  if (i < e) {
    int d = dst[i], s = src[i];
    int pos = atomicAdd(&cursor[d], 1);
    csr[pos] = make_int2(s, __float_as_int(dinv[s] * dinv[d]));
  }
}

// ---------------- conversions (x + all weights, one kernel) ----------------
// Bt layouts: plain Bt[n*K + k] = f16(W[k*N + n]); out split: [n][kp], kp<256 hi,
// 256..512 lo, 512..768 hi.
#define X_Q (N_NODES * DIN / 4)        // 1,600,000 float4 groups
#define W_EMB_SZ (DIN * DH)            // 32768
#define W_CONV_SZ (DH * DH)            // 65536
#define W_OUT_SZ (3 * DH * DOUT)       // 49152
#define W_TOT (W_EMB_SZ + 4 * W_CONV_SZ + W_OUT_SZ)

__global__ void k_convert(const float* __restrict__ x, u16* __restrict__ x_f16,
                          const float* __restrict__ W_emb, const float* __restrict__ W_conv,
                          const float* __restrict__ W_out, u16* __restrict__ Bt_emb,
                          u16* __restrict__ Bt_conv, u16* __restrict__ Bt_out) {
  int i = blockIdx.x * 256 + threadIdx.x;
  if (i < X_Q) {
    float4 v = ((const float4*)x)[i];
    ushort4 o;
    o.x = f2h(v.x); o.y = f2h(v.y); o.z = f2h(v.z); o.w = f2h(v.w);
    ((ushort4*)x_f16)[i] = o;
    return;
  }
  int t = i - X_Q;
  if (t < W_EMB_SZ) {
    int n = t >> 7, k = t & (DIN - 1);
    Bt_emb[t] = f2h(W_emb[k * DH + n]);
  } else if (t < W_EMB_SZ + 4 * W_CONV_SZ) {
    int j = t - W_EMB_SZ;
    int l = j >> 16, jj = j & (W_CONV_SZ - 1);
    int n = jj >> 8, k = jj & (DH - 1);
    Bt_conv[j] = f2h(W_conv[l * W_CONV_SZ + k * DH + n]);
  } else if (t < W_TOT) {
    int j = t - W_EMB_SZ - 4 * W_CONV_SZ;
    int n = j / (3 * DH), kp = j % (3 * DH);
    int k = (kp < DH) ? kp : ((kp < 2 * DH) ? kp - DH : kp - 2 * DH);
    float wv = W_out[k * DOUT + n];
    u16 hiv = f2h(wv);
    u16 v = hiv;
    if (kp >= DH && kp < 2 * DH) v = f2h(wv - h2f(hiv));
    Bt_out[j] = v;
  }
}

// ---------------- f16 MFMA GEMM (round-4 LDS structure) ----------------
// C[M][N] = A[M][K']·B2[K'][N], A given as (Ahi, Alo) f16 [M][K].
// NSPLIT=1: K'=K. NSPLIT=3: K'=3K, (Ahi·Bhi)+(Ahi·Blo)+(Alo·Bhi).
// Bt = B2^T [N][K'] f16. BM=128, BK=64, 4 waves, wave tile 64 x (BN/2).
// LDS is FRAGMENT-ORDER: slot (kb, g) holds 16 rows x 32 k as 64 lane-fragments
// of 16 B -> staging (GLD16 lane*16) and fragment ds_read_b128 (lane-consecutive)
// are both conflict-free by construction.
// EPI 0: Cf fp32 (+bias); EPI 1: Cb f16 (+bias).
template <int BN, int NSPLIT, int EPI>
__global__ __launch_bounds__(256) void k_gemm_mfma(
    const u16* __restrict__ Ahi, const u16* __restrict__ Alo,
    const u16* __restrict__ Bt, const float* __restrict__ bias,
    float* __restrict__ Cf, u16* __restrict__ Cb, int M, int K, int N) {
  constexpr int BM = 128, BK = 64;
  constexpr int WN = BN / 2;
  constexpr int NT = WN / 16;
  constexpr int BNG = BN / 16;  // B row-groups
  __shared__ u16 As[2 * 8 * 512];     // (kb, g<8, lane*8) : 16 KB
  __shared__ u16 Bs[2 * BNG * 512];   // (kb, g<BNG, lane*8)
  const int tid = threadIdx.x;
  const int w = tid >> 6, lane = tid & 63;
  const int q = lane >> 4, r = lane & 15;
  const int wmg = (w >> 1) * 4;       // A group base for this wave
  const int wng = (w & 1) * NT;       // B group base
  const int m0 = blockIdx.x * BM, n0 = blockIdx.y * BN;
  const int Kp = NSPLIT * K;
  const int srow = lane & 15;         // staging source row within group
  const int sk = (lane >> 4) * 8;     // staging source k offset

  f32x4 acc[4][NT];
#pragma unroll
  for (int t = 0; t < 4; t++)
#pragma unroll
    for (int u = 0; u < NT; u++) acc[t][u] = (f32x4){0.f, 0.f, 0.f, 0.f};

  for (int k0 = 0; k0 < Kp; k0 += BK) {
    const u16* Aptr;
    int ka;
    if (NSPLIT == 1) {
      Aptr = Ahi; ka = k0;
    } else {
      Aptr = (k0 < 2 * K) ? Ahi : Alo;
      ka = (k0 < K) ? k0 : ((k0 < 2 * K) ? (k0 - K) : (k0 - 2 * K));
    }
    // stage A: 16 slots over 4 waves x 4 issues
#pragma unroll
    for (int ii = 0; ii < 4; ii++) {
      int g = w * 2 + (ii & 1), kb = ii >> 1;
      int grow = m0 + g * 16 + srow;
      if (grow > M - 1) grow = M - 1;
      const u16* gp = Aptr + (size_t)grow * K + ka + kb * 32 + sk;
      GLD16(gp, &As[(kb * 8 + g) * 512] + (size_t)lane * 8);
    }
    // stage B: 2*BNG slots over 4 waves x (BN/32) issues
#pragma unroll
    for (int ii = 0; ii < BN / 32; ii++) {
      int g, kb;
      if (BN == 128) { g = w * 2 + (ii & 1); kb = ii >> 1; }
      else { g = w; kb = ii; }
      const u16* gp = Bt + (size_t)(n0 + g * 16 + srow) * Kp + k0 + kb * 32 + sk;
      GLD16(gp, &Bs[(kb * BNG + g) * 512] + (size_t)lane * 8);
    }
    __syncthreads();
#pragma unroll
    for (int kb = 0; kb < 2; kb++) {
      half8 af[4], bfr[NT];
#pragma unroll
      for (int t = 0; t < 4; t++)
        af[t] = *(const half8*)&As[((kb * 8 + wmg + t) * 64 + lane) * 8];
#pragma unroll
      for (int u = 0; u < NT; u++)
        bfr[u] = *(const half8*)&Bs[((kb * BNG + wng + u) * 64 + lane) * 8];
#pragma unroll
      for (int t = 0; t < 4; t++)
#pragma unroll
        for (int u = 0; u < NT; u++)
          acc[t][u] = __builtin_amdgcn_mfma_f32_16x16x32_f16(af[t], bfr[u], acc[t][u], 0, 0, 0);
    }
    __syncthreads();
  }

#pragma unroll
  for (int t = 0; t < 4; t++) {
#pragma unroll
    for (int rg = 0; rg < 4; rg++) {
      int row = m0 + (w >> 1) * 64 + t * 16 + q * 4 + rg;
      if (row < M) {
#pragma unroll
        for (int u = 0; u < NT; u++) {
          int col = n0 + (w & 1) * WN + u * 16 + r;
          float v = acc[t][u][rg];
          if (bias) v += bias[col];
          if (EPI == 0)
            Cf[(size_t)row * N + col] = v;
          else
            Cb[(size_t)row * N + col] = f2h(v);
        }
      }
    }
  }
}

// ---------------- aggregation (f16 in, unroll-8 gathers) ----------------
// h[i] = tanh(b + dinv[i]^2*tmp[i] + sum_e w_e*tmp[src_e]); writes f16 hi (+lo).
__global__ void k_aggregate(const u16* __restrict__ tmph,
                            const int* __restrict__ rowptr, const int2* __restrict__ csr,
                            const float* __restrict__ dinv, const float* __restrict__ bias,
                            u16* __restrict__ hi, u16* __restrict__ lo, int n) {
  int i = (int)((blockIdx.x * (size_t)blockDim.x + threadIdx.x) >> 6);
  int lane = threadIdx.x & 63;
  if (i >= n) return;
  float w0 = dinv[i];
  w0 *= w0;
  const ushort4* T = (const ushort4*)tmph;
  float4 bv = ((const float4*)bias)[lane];
  ushort4 t0 = T[(size_t)i * 64 + lane];
  float ax = bv.x + w0 * h2f(t0.x);
  float ay = bv.y + w0 * h2f(t0.y);
  float az = bv.z + w0 * h2f(t0.z);
  float aw = bv.w + w0 * h2f(t0.w);
  int s = rowptr[i], e = rowptr[i + 1];
  int j = s;
  for (; j + 8 <= e; j += 8) {
    int2 c[8];
    ushort4 v[8];
#pragma unroll
    for (int u = 0; u < 8; u++) c[u] = csr[j + u];
#pragma unroll
    for (int u = 0; u < 8; u++) v[u] = T[(size_t)c[u].x * 64 + lane];
#pragma unroll
    for (int u = 0; u < 8; u++) {
      float f = __int_as_float(c[u].y);
      ax += f * h2f(v[u].x);
      ay += f * h2f(v[u].y);
      az += f * h2f(v[u].z);
      aw += f * h2f(v[u].w);
    }
  }
  for (; j + 4 <= e; j += 4) {
    int2 c[4];
    ushort4 v[4];
#pragma unroll
    for (int u = 0; u < 4; u++) c[u] = csr[j + u];
#pragma unroll
    for (int u = 0; u < 4; u++) v[u] = T[(size_t)c[u].x * 64 + lane];
#pragma unroll
    for (int u = 0; u < 4; u++) {
      float f = __int_as_float(c[u].y);
      ax += f * h2f(v[u].x);
      ay += f * h2f(v[u].y);
      az += f * h2f(v[u].z);
      aw += f * h2f(v[u].w);
    }
  }
  for (; j < e; j++) {
    int2 c = csr[j];
    ushort4 v = T[(size_t)c.x * 64 + lane];
    float f = __int_as_float(c.y);
    ax += f * h2f(v.x);
    ay += f * h2f(v.y);
    az += f * h2f(v.z);
    aw += f * h2f(v.w);
  }
  float ox = tanhf(ax), oy = tanhf(ay), oz = tanhf(az), ow = tanhf(aw);
  size_t base = (size_t)i * DH + lane * 4;
  ushort4 hv;
  hv.x = f2h(ox); hv.y = f2h(oy); hv.z = f2h(oz); hv.w = f2h(ow);
  *(ushort4*)(hi + base) = hv;
  if (lo) {
    ushort4 lv;
    lv.x = f2h(ox - h2f(hv.x));
    lv.y = f2h(oy - h2f(hv.y));
    lv.z = f2h(oz - h2f(hv.z));
    lv.w = f2h(ow - h2f(hv.w));
    *(ushort4*)(lo + base) = lv;
  }
}

// ---------------- launch ----------------

extern "C" void kernel_launch(void* const* d_in, const int* in_sizes, int n_in,
                              void* d_out, int out_size, void* d_ws, size_t ws_size,
                              hipStream_t stream) {
  const float* x = (const float*)d_in[0];
  const int* eidx = (const int*)d_in[1];
  const int* esrc = eidx;
  const int* edst = eidx + N_EDGES;
  const float* W_emb = (const float*)d_in[2];
  const float* b_emb = (const float*)d_in[3];
  const float* W_conv = (const float*)d_in[4];
  const float* b_conv = (const float*)d_in[5];
  const float* W_out = (const float*)d_in[6];
  const float* b_out = (const float*)d_in[7];
  float* out = (float*)d_out;

  char* ws = (char*)d_ws;
  size_t off = 0;
  auto alloc = [&](size_t bytes) -> void* {
    void* p = ws + off;
    off += (bytes + 255) & ~(size_t)255;
    return p;
  };
  u16* tmph = (u16*)alloc((size_t)N_NODES * DH * 2);
  u16* h_hi = (u16*)alloc((size_t)N_NODES * DH * 2);
  u16* h_lo = (u16*)alloc((size_t)N_NODES * DH * 2);
  u16* x_f16 = h_lo;  // alias: x_f16 dead after emb GEMM; h_lo first written at layer-3 agg
  float* dinv = (float*)alloc((size_t)N_NODES * 4);
  int* cnt = (int*)alloc((size_t)N_NODES * 4);
  int* rowptr = (int*)alloc((size_t)(N_NODES + 1) * 4);
  int* cursor = (int*)alloc((size_t)N_NODES * 4);
  int* bsum = (int*)alloc((size_t)((N_NODES + 255) / 256) * 4);
  int2* csr = (int2*)alloc((size_t)N_EDGES * 8);
  u16* Bt_emb = (u16*)alloc((size_t)W_EMB_SZ * 2);
  u16* Bt_conv = (u16*)alloc((size_t)4 * W_CONV_SZ * 2);
  u16* Bt_out = (u16*)alloc((size_t)W_OUT_SZ * 2);

  int nb = (N_NODES + 255) / 256;
  int eb = (N_EDGES + 255) / 256;

  hipMemsetAsync(cnt, 0, (size_t)N_NODES * 4, stream);
  k_count<<<eb, 256, 0, stream>>>(edst, cnt, N_EDGES);
  k_scan1<<<nb, 256, 0, stream>>>(cnt, rowptr, bsum, dinv, N_NODES);
  k_scan2<<<1, 256, 0, stream>>>(bsum, nb);
  k_scan3<<<nb, 256, 0, stream>>>(rowptr, bsum, cursor, N_NODES);
  k_fill<<<eb, 256, 0, stream>>>(esrc, edst, dinv, cursor, csr, N_EDGES);
  k_convert<<<(X_Q + W_TOT + 255) / 256, 256, 0, stream>>>(x, x_f16, W_emb, W_conv, W_out,
                                                           Bt_emb, Bt_conv, Bt_out);

  int mblocks = (N_NODES + 127) / 128;  // 391
  int aggblocks = (N_NODES * 64 + 255) / 256;

  // emb: h0 = x @ W_emb + b_emb  -> f16 h_hi
  {
    dim3 g(mblocks, DH / 128);
    k_gemm_mfma<128, 1, 1><<<g, 256, 0, stream>>>(x_f16, nullptr, Bt_emb, b_emb,
                                                  nullptr, h_hi, N_NODES, DIN, DH);
  }
  // conv layers: plain f16; layer 3 agg also emits h_lo for the final split GEMM
  for (int l = 0; l < NLAYERS; l++) {
    dim3 g(mblocks, DH / 128);
    k_gemm_mfma<128, 1, 1><<<g, 256, 0, stream>>>(h_hi, nullptr,
                                                  Bt_conv + (size_t)l * W_CONV_SZ, nullptr,
                                                  nullptr, tmph, N_NODES, DH, DH);
    k_aggregate<<<aggblocks, 256, 0, stream>>>(tmph, rowptr, csr, dinv,
                                               b_conv + (size_t)l * DH,
                                               h_hi, (l == 3) ? h_lo : nullptr, N_NODES);
  }
  // out = h4 @ W_out + b_out (split-3, fp32 out)
  {
    dim3 g(mblocks, 1);
    k_gemm_mfma<64, 3, 0><<<g, 256, 0, stream>>>(h_hi, h_lo, Bt_out, b_out,
                                                 out, nullptr, N_NODES, DH, DOUT);
  }
}

// Round 7
// 562.982 us; speedup vs baseline: 1.0877x; 1.0066x over previous
//
#include <hip/hip_runtime.h>
#include <math.h>

#define N_NODES 50000
#define N_EDGES 800000
#define DIN 128
#define DH 256
#define DOUT 64
#define NLAYERS 4

typedef unsigned short u16;
typedef __attribute__((ext_vector_type(8))) _Float16 half8;
typedef __attribute__((ext_vector_type(4))) float f32x4;

__device__ inline u16 f2h(float f) {
  _Float16 h = (_Float16)f;
  return *(u16*)&h;
}
__device__ inline float h2f(u16 u) {
  _Float16 h = *(_Float16*)&u;
  return (float)h;
}
// stored index j -> true feature index (perm: true c -> (c%16)*4 + c/16 per 64-seg)
__device__ inline int invp(int j) {
  int s = j >> 6, t = j & 63;
  return s * 64 + (t & 3) * 16 + (t >> 2);
}

#define GLD16(gp, lp)                                                        \
  __builtin_amdgcn_global_load_lds(                                          \
      (const __attribute__((address_space(1))) void*)(const void*)(gp),      \
      (__attribute__((address_space(3))) void*)(void*)(lp), 16, 0, 0)

// ---------------- preprocessing ----------------

// scan1 + dinv fused
__global__ void k_scan1(const int* __restrict__ cnt, int* __restrict__ rowptr,
                        int* __restrict__ bsum, float* __restrict__ dinv, int n) {
  __shared__ int sm[256];
  int i = blockIdx.x * 256 + threadIdx.x;
  int v = (i < n) ? cnt[i] : 0;
  if (i < n) dinv[i] = rsqrtf((float)v + 1.0f);  // +1 = self-loop
  sm[threadIdx.x] = v;
  __syncthreads();
  for (int off = 1; off < 256; off <<= 1) {
    int t = (threadIdx.x >= off) ? sm[threadIdx.x - off] : 0;
    __syncthreads();
    sm[threadIdx.x] += t;
    __syncthreads();
  }
  if (i < n) rowptr[i + 1] = sm[threadIdx.x];
  if (threadIdx.x == 255) bsum[blockIdx.x] = sm[255];
}

__global__ void k_scan2(int* bsum, int nb) {
  __shared__ int sm[256];
  int v = (threadIdx.x < nb) ? bsum[threadIdx.x] : 0;
  sm[threadIdx.x] = v;
  __syncthreads();
  for (int off = 1; off < 256; off <<= 1) {
    int t = (threadIdx.x >= off) ? sm[threadIdx.x - off] : 0;
    __syncthreads();
    sm[threadIdx.x] += t;
    __syncthreads();
  }
  if (threadIdx.x < nb) bsum[threadIdx.x] = sm[threadIdx.x] - v;
}

// scan3 + cursor init fused
__global__ void k_scan3(int* __restrict__ rowptr, const int* __restrict__ bsum,
                        int* __restrict__ cursor, int n) {
  int i = blockIdx.x * 256 + threadIdx.x;
  if (i < n) {
    int v = rowptr[i + 1] + bsum[blockIdx.x];
    rowptr[i + 1] = v;
    if (i + 1 < n) cursor[i + 1] = v;
  }
  if (blockIdx.x == 0 && threadIdx.x == 0) {
    rowptr[0] = 0;
    cursor[0] = 0;
  }
}

__global__ void k_fill(const int* __restrict__ src, const int* __restrict__ dst,
                       const float* __restrict__ dinv,
                       int* __restrict__ cursor, int2* __restrict__ csr, int e) {
  int i = blockIdx.x * blockDim.x + threadIdx.x;
  if (i < e) {
    int d = dst[i], s = src[i];
    int pos = atomicAdd(&cursor[d], 1);
    csr[pos] = make_int2(s, __float_as_int(dinv[s] * dinv[d]));
  }
}

// ---------------- convert: x, weights (k-inverse-perm), biases (perm), + count ----
#define X_Q (N_NODES * DIN / 4)        // 1,600,000 float4 groups
#define W_EMB_SZ (DIN * DH)            // 32768 (plain: emb k-dim is unpermuted x)
#define W_CONV_SZ (DH * DH)            // 65536
#define W_OUT_SZ (3 * DH * DOUT)       // 49152
#define W_TOT (W_EMB_SZ + 4 * W_CONV_SZ + W_OUT_SZ)
#define B_TOT (DH + 4 * DH)            // permuted b_emb + b_conv

__global__ void k_convert(const float* __restrict__ x, u16* __restrict__ x_f16,
                          const float* __restrict__ W_emb, const float* __restrict__ W_conv,
                          const float* __restrict__ W_out,
                          const float* __restrict__ b_emb, const float* __restrict__ b_conv,
                          u16* __restrict__ Bt_emb, u16* __restrict__ Bt_conv,
                          u16* __restrict__ Bt_out,
                          float* __restrict__ bEmbP, float* __restrict__ bConvP,
                          const int* __restrict__ edst, int* __restrict__ cnt) {
  int i = blockIdx.x * 256 + threadIdx.x;
  if (i < X_Q) {
    float4 v = ((const float4*)x)[i];
    ushort4 o;
    o.x = f2h(v.x); o.y = f2h(v.y); o.z = f2h(v.z); o.w = f2h(v.w);
    ((ushort4*)x_f16)[i] = o;
    return;
  }
  int t = i - X_Q;
  if (t < W_EMB_SZ) {
    int n = t >> 7, k = t & (DIN - 1);           // Bt_emb[n][k], k plain
    Bt_emb[t] = f2h(W_emb[k * DH + n]);
  } else if (t < W_EMB_SZ + 4 * W_CONV_SZ) {
    int j = t - W_EMB_SZ;
    int l = j >> 16, jj = j & (W_CONV_SZ - 1);
    int n = jj >> 8, k2 = jj & (DH - 1);         // Bt_conv[n][k2], k2 = perm space
    Bt_conv[j] = f2h(W_conv[l * W_CONV_SZ + invp(k2) * DH + n]);
  } else if (t < W_TOT) {
    int j = t - W_EMB_SZ - 4 * W_CONV_SZ;
    int n = j / (3 * DH), kp = j % (3 * DH);     // Bt_out[n][kp]: 0..255 hi,256.. lo,512.. hi
    int s0 = kp >> 8, k2 = kp & (DH - 1);
    float wv = W_out[invp(k2) * DOUT + n];
    u16 hiv = f2h(wv);
    u16 v = hiv;
    if (s0 == 1) v = f2h(wv - h2f(hiv));
    Bt_out[j] = v;
  } else {
    int t2 = t - W_TOT;
    if (t2 < B_TOT) {
      if (t2 < DH) bEmbP[t2] = b_emb[invp(t2)];
      else {
        int j = t2 - DH, l = j >> 8, jj = j & (DH - 1);
        bConvP[j] = b_conv[l * DH + invp(jj)];
      }
    } else {
      int t3 = t2 - B_TOT;
      if (t3 < N_EDGES) atomicAdd(&cnt[edst[t3]], 1);
    }
  }
}

// ---------------- f16 MFMA GEMM: A via LDS, B direct from L2 ----------------
// C[M][N] = A[M][K']·B2[K'][N]; A = (Ahi, Alo) f16 [M][K] (feature order = caller's).
// NSPLIT=1: K'=K. NSPLIT=3: K'=3K, (Ahi·Bhi)+(Ahi·Blo)+(Alo·Bhi); Bt segments
// [0,K) hi, [K,2K) lo, [2K,3K) hi. Bt = B2^T [N][K'] f16 (L2-resident weight).
// BM=128, BK=64, 4 waves, wave tile 64 x (BN/2). A staged via GLD16 in
// fragment-order LDS (conflict-free); B fragments loaded straight to VGPRs.
// EPI 0: Cf fp32 + bias, TRUE col order (scalar stores).
// EPI 1: Cb f16 + biasp, PERM col order (ushort4 stores); requires BN=128.
template <int BN, int NSPLIT, int EPI>
__global__ __launch_bounds__(256) void k_gemm_mfma(
    const u16* __restrict__ Ahi, const u16* __restrict__ Alo,
    const u16* __restrict__ Bt, const float* __restrict__ bias,
    float* __restrict__ Cf, u16* __restrict__ Cb, int M, int K, int N) {
  constexpr int BM = 128, BK = 64;
  constexpr int WN = BN / 2;
  constexpr int NT = WN / 16;
  __shared__ u16 As[2 * 8 * 512];  // (kb, g<8, lane*8) : 16 KB
  const int tid = threadIdx.x;
  const int w = tid >> 6, lane = tid & 63;
  const int q = lane >> 4, r = lane & 15;
  const int wmg = (w >> 1) * 4;       // A group base for this wave
  const int wn = (w & 1) * WN;
  const int m0 = blockIdx.x * BM, n0 = blockIdx.y * BN;
  const int Kp = NSPLIT * K;
  const int srow = lane & 15;         // staging source row within group
  const int sk = (lane >> 4) * 8;     // staging source k offset

  f32x4 acc[4][NT];
#pragma unroll
  for (int t = 0; t < 4; t++)
#pragma unroll
    for (int u = 0; u < NT; u++) acc[t][u] = (f32x4){0.f, 0.f, 0.f, 0.f};

  for (int k0 = 0; k0 < Kp; k0 += BK) {
    const u16* Aptr;
    int ka;
    if (NSPLIT == 1) {
      Aptr = Ahi; ka = k0;
    } else {
      Aptr = (k0 < 2 * K) ? Ahi : Alo;
      ka = (k0 < K) ? k0 : ((k0 < 2 * K) ? (k0 - K) : (k0 - 2 * K));
    }
    // stage A: 16 slots over 4 waves x 4 issues
#pragma unroll
    for (int ii = 0; ii < 4; ii++) {
      int g = w * 2 + (ii & 1), kb = ii >> 1;
      int grow = m0 + g * 16 + srow;
      if (grow > M - 1) grow = M - 1;
      const u16* gp = Aptr + (size_t)grow * K + ka + kb * 32 + sk;
      GLD16(gp, &As[(kb * 8 + g) * 512] + (size_t)lane * 8);
    }
    __syncthreads();
#pragma unroll
    for (int kb = 0; kb < 2; kb++) {
      half8 af[4], bfr[NT];
#pragma unroll
      for (int u = 0; u < NT; u++)
        bfr[u] = *(const half8*)(Bt + (size_t)(n0 + wn + u * 16 + r) * Kp +
                                 k0 + kb * 32 + q * 8);
#pragma unroll
      for (int t = 0; t < 4; t++)
        af[t] = *(const half8*)&As[((kb * 8 + wmg + t) * 64 + lane) * 8];
#pragma unroll
      for (int t = 0; t < 4; t++)
#pragma unroll
        for (int u = 0; u < NT; u++)
          acc[t][u] = __builtin_amdgcn_mfma_f32_16x16x32_f16(af[t], bfr[u], acc[t][u], 0, 0, 0);
    }
    __syncthreads();
  }

  if (EPI == 1) {
    // perm epilogue: lane holds true cols cb+u*16+r -> stored cb + r*4 + u
    int cb = n0 + wn;
    float4 bp = bias ? *(const float4*)(bias + cb + r * 4)
                     : make_float4(0.f, 0.f, 0.f, 0.f);
#pragma unroll
    for (int t = 0; t < 4; t++) {
#pragma unroll
      for (int rg = 0; rg < 4; rg++) {
        int row = m0 + (w >> 1) * 64 + t * 16 + q * 4 + rg;
        if (row < M) {
          ushort4 o;
          o.x = f2h(acc[t][0][rg] + bp.x);
          o.y = f2h(acc[t][1][rg] + bp.y);
          o.z = f2h(acc[t][2][rg] + bp.z);
          o.w = f2h(acc[t][3][rg] + bp.w);
          *(ushort4*)(Cb + (size_t)row * N + cb + r * 4) = o;
        }
      }
    }
  } else {
    float bv[NT];
#pragma unroll
    for (int u = 0; u < NT; u++) bv[u] = bias ? bias[n0 + wn + u * 16 + r] : 0.f;
#pragma unroll
    for (int t = 0; t < 4; t++) {
#pragma unroll
      for (int rg = 0; rg < 4; rg++) {
        int row = m0 + (w >> 1) * 64 + t * 16 + q * 4 + rg;
        if (row < M) {
#pragma unroll
          for (int u = 0; u < NT; u++) {
            int col = n0 + wn + u * 16 + r;
            Cf[(size_t)row * N + col] = acc[t][u][rg] + bv[u];
          }
        }
      }
    }
  }
}

// ---------------- aggregation (f16 in, unroll-8 gathers; feature order = perm) ----
// h[i] = tanh(b + dinv[i]^2*tmp[i] + sum_e w_e*tmp[src_e]); writes f16 hi (+lo).
__global__ void k_aggregate(const u16* __restrict__ tmph,
                            const int* __restrict__ rowptr, const int2* __restrict__ csr,
                            const float* __restrict__ dinv, const float* __restrict__ bias,
                            u16* __restrict__ hi, u16* __restrict__ lo, int n) {
  int i = (int)((blockIdx.x * (size_t)blockDim.x + threadIdx.x) >> 6);
  int lane = threadIdx.x & 63;
  if (i >= n) return;
  float w0 = dinv[i];
  w0 *= w0;
  const ushort4* T = (const ushort4*)tmph;
  float4 bv = ((const float4*)bias)[lane];
  ushort4 t0 = T[(size_t)i * 64 + lane];
  float ax = bv.x + w0 * h2f(t0.x);
  float ay = bv.y + w0 * h2f(t0.y);
  float az = bv.z + w0 * h2f(t0.z);
  float aw = bv.w + w0 * h2f(t0.w);
  int s = rowptr[i], e = rowptr[i + 1];
  int j = s;
  for (; j + 8 <= e; j += 8) {
    int2 c[8];
    ushort4 v[8];
#pragma unroll
    for (int u = 0; u < 8; u++) c[u] = csr[j + u];
#pragma unroll
    for (int u = 0; u < 8; u++) v[u] = T[(size_t)c[u].x * 64 + lane];
#pragma unroll
    for (int u = 0; u < 8; u++) {
      float f = __int_as_float(c[u].y);
      ax += f * h2f(v[u].x);
      ay += f * h2f(v[u].y);
      az += f * h2f(v[u].z);
      aw += f * h2f(v[u].w);
    }
  }
  for (; j + 4 <= e; j += 4) {
    int2 c[4];
    ushort4 v[4];
#pragma unroll
    for (int u = 0; u < 4; u++) c[u] = csr[j + u];
#pragma unroll
    for (int u = 0; u < 4; u++) v[u] = T[(size_t)c[u].x * 64 + lane];
#pragma unroll
    for (int u = 0; u < 4; u++) {
      float f = __int_as_float(c[u].y);
      ax += f * h2f(v[u].x);
      ay += f * h2f(v[u].y);
      az += f * h2f(v[u].z);
      aw += f * h2f(v[u].w);
    }
  }
  for (; j < e; j++) {
    int2 c = csr[j];
    ushort4 v = T[(size_t)c.x * 64 + lane];
    float f = __int_as_float(c.y);
    ax += f * h2f(v.x);
    ay += f * h2f(v.y);
    az += f * h2f(v.z);
    aw += f * h2f(v.w);
  }
  float ox = tanhf(ax), oy = tanhf(ay), oz = tanhf(az), ow = tanhf(aw);
  size_t base = (size_t)i * DH + lane * 4;
  ushort4 hv;
  hv.x = f2h(ox); hv.y = f2h(oy); hv.z = f2h(oz); hv.w = f2h(ow);
  *(ushort4*)(hi + base) = hv;
  if (lo) {
    ushort4 lv;
    lv.x = f2h(ox - h2f(hv.x));
    lv.y = f2h(oy - h2f(hv.y));
    lv.z = f2h(oz - h2f(hv.z));
    lv.w = f2h(ow - h2f(hv.w));
    *(ushort4*)(lo + base) = lv;
  }
}

// ---------------- launch ----------------

extern "C" void kernel_launch(void* const* d_in, const int* in_sizes, int n_in,
                              void* d_out, int out_size, void* d_ws, size_t ws_size,
                              hipStream_t stream) {
  const float* x = (const float*)d_in[0];
  const int* eidx = (const int*)d_in[1];
  const int* esrc = eidx;
  const int* edst = eidx + N_EDGES;
  const float* W_emb = (const float*)d_in[2];
  const float* b_emb = (const float*)d_in[3];
  const float* W_conv = (const float*)d_in[4];
  const float* b_conv = (const float*)d_in[5];
  const float* W_out = (const float*)d_in[6];
  const float* b_out = (const float*)d_in[7];
  float* out = (float*)d_out;

  char* ws = (char*)d_ws;
  size_t off = 0;
  auto alloc = [&](size_t bytes) -> void* {
    void* p = ws + off;
    off += (bytes + 255) & ~(size_t)255;
    return p;
  };
  u16* tmph = (u16*)alloc((size_t)N_NODES * DH * 2);
  u16* h_hi = (u16*)alloc((size_t)N_NODES * DH * 2);
  u16* h_lo = (u16*)alloc((size_t)N_NODES * DH * 2);
  u16* x_f16 = h_lo;  // alias: x_f16 dead after emb GEMM; h_lo first written at layer-3 agg
  float* dinv = (float*)alloc((size_t)N_NODES * 4);
  int* cnt = (int*)alloc((size_t)N_NODES * 4);
  int* rowptr = (int*)alloc((size_t)(N_NODES + 1) * 4);
  int* cursor = (int*)alloc((size_t)N_NODES * 4);
  int* bsum = (int*)alloc((size_t)((N_NODES + 255) / 256) * 4);
  int2* csr = (int2*)alloc((size_t)N_EDGES * 8);
  u16* Bt_emb = (u16*)alloc((size_t)W_EMB_SZ * 2);
  u16* Bt_conv = (u16*)alloc((size_t)4 * W_CONV_SZ * 2);
  u16* Bt_out = (u16*)alloc((size_t)W_OUT_SZ * 2);
  float* bEmbP = (float*)alloc((size_t)DH * 4);
  float* bConvP = (float*)alloc((size_t)4 * DH * 4);

  int nb = (N_NODES + 255) / 256;
  int eb = (N_EDGES + 255) / 256;

  hipMemsetAsync(cnt, 0, (size_t)N_NODES * 4, stream);
  {
    int tot = X_Q + W_TOT + B_TOT + N_EDGES;
    k_convert<<<(tot + 255) / 256, 256, 0, stream>>>(x, x_f16, W_emb, W_conv, W_out,
                                                     b_emb, b_conv, Bt_emb, Bt_conv,
                                                     Bt_out, bEmbP, bConvP, edst, cnt);
  }
  k_scan1<<<nb, 256, 0, stream>>>(cnt, rowptr, bsum, dinv, N_NODES);
  k_scan2<<<1, 256, 0, stream>>>(bsum, nb);
  k_scan3<<<nb, 256, 0, stream>>>(rowptr, bsum, cursor, N_NODES);
  k_fill<<<eb, 256, 0, stream>>>(esrc, edst, dinv, cursor, csr, N_EDGES);

  int mblocks = (N_NODES + 127) / 128;  // 391
  int aggblocks = (N_NODES * 64 + 255) / 256;

  // emb: h0 = x @ W_emb + b_emb  -> f16 h_hi (perm cols)
  {
    dim3 g(mblocks, DH / 128);
    k_gemm_mfma<128, 1, 1><<<g, 256, 0, stream>>>(x_f16, nullptr, Bt_emb, bEmbP,
                                                  nullptr, h_hi, N_NODES, DIN, DH);
  }
  // conv layers: plain f16; layer 3 agg also emits h_lo for the final split GEMM
  for (int l = 0; l < NLAYERS; l++) {
    dim3 g(mblocks, DH / 128);
    k_gemm_mfma<128, 1, 1><<<g, 256, 0, stream>>>(h_hi, nullptr,
                                                  Bt_conv + (size_t)l * W_CONV_SZ, nullptr,
                                                  nullptr, tmph, N_NODES, DH, DH);
    k_aggregate<<<aggblocks, 256, 0, stream>>>(tmph, rowptr, csr, dinv,
                                               bConvP + (size_t)l * DH,
                                               h_hi, (l == 3) ? h_lo : nullptr, N_NODES);
  }
  // out = h4 @ W_out + b_out (split-3, fp32 out, TRUE col order)
  {
    dim3 g(mblocks, 1);
    k_gemm_mfma<64, 3, 0><<<g, 256, 0, stream>>>(h_hi, h_lo, Bt_out, b_out,
                                                 out, nullptr, N_NODES, DH, DOUT);
  }
}